// Round 6
// baseline (182.278 us; speedup 1.0000x reference)
//
#include <hip/hip_runtime.h>
#include <math.h>

// DynamicNTXentLoss on MI355X — r4: persistent waves + double-buffered
// prefetch. Inputs: zis (65536,256) f32, zjs (65536,256) f32,
// soft_labels (4,3) f32. Output: scalar f32 loss.
//
// Layout: wave = 4 subgroups x 16 lanes; subgroup q handles group quad*4+q.
// Lane t owns floats [t*4 + c*64, +4), c=0..3, of each of 4 rows.
// r1-r3 were latency-bound (~45 µs, 2.8 TB/s, all pipes <35%): one quad
// per wave = pure ramp/drain, no steady state. r4: 512 blocks (2/CU,
// 8 waves/CU), 4 quads/wave, prefetch next quad's 16 loads (names vA/vB,
// all static indexing) while computing the current one.

constexpr int D = 256;

__device__ __forceinline__ float dot4(float4 a, float4 b) {
    return fmaf(a.x, b.x, fmaf(a.y, b.y, fmaf(a.z, b.z, a.w * b.w)));
}

template <int CTRL>
__device__ __forceinline__ float dpp_add(float x) {
    int y = __builtin_amdgcn_update_dpp(0, __float_as_int(x), CTRL, 0xF, 0xF, true);
    return x + __int_as_float(y);
}

// sum across the 16-lane subgroup; all 16 lanes get the total
__device__ __forceinline__ float red16(float x) {
    x = dpp_add<0xB1>(x);   // quad_perm xor1
    x = dpp_add<0x4E>(x);   // quad_perm xor2
    x = dpp_add<0x124>(x);  // row_ror:4
    x = dpp_add<0x128>(x);  // row_ror:8
    return x;
}

__device__ __forceinline__ float rowloss(float a, float b, float c,
                                         float s0, float s1, float s2) {
    float m = fmaxf(fmaxf(a, b), c);
    float lse = m + __logf(__expf(a - m) + __expf(b - m) + __expf(c - m));
    return s0 * (lse - a) + s1 * (lse - b) + s2 * (lse - c);
}

__device__ __forceinline__ void load_quad(float4 v[16],
                                          const float* __restrict__ zis,
                                          const float* __restrict__ zjs,
                                          int gc, int o) {
    const float* rj = zjs + (size_t)(2 * gc) * D;
    const float* ri = zis + (size_t)(2 * gc) * D;
#pragma unroll
    for (int c = 0; c < 4; ++c) {
        v[c]      = *(const float4*)(rj + c * 64 + o);
        v[4 + c]  = *(const float4*)(rj + D + c * 64 + o);
        v[8 + c]  = *(const float4*)(ri + c * 64 + o);
        v[12 + c] = *(const float4*)(ri + D + c * 64 + o);
    }
}

struct SL { float s[12]; };

__device__ __forceinline__ float compute_quad(const float4 v[16], bool valid,
                                              const SL& L) {
    float n0 = 0, n1 = 0, n2 = 0, n3 = 0;
    float d01 = 0, d02 = 0, d03 = 0, d12 = 0, d13 = 0, d23 = 0;
#pragma unroll
    for (int c = 0; c < 4; ++c) {
        const float4 a = v[c], b = v[4 + c], cc = v[8 + c], d = v[12 + c];
        n0 += dot4(a, a);   n1 += dot4(b, b);
        n2 += dot4(cc, cc); n3 += dot4(d, d);
        d01 += dot4(a, b);  d02 += dot4(a, cc);
        d03 += dot4(a, d);  d12 += dot4(b, cc);
        d13 += dot4(b, d);  d23 += dot4(cc, d);
    }
    n0 = red16(n0);  n1 = red16(n1);  n2 = red16(n2);  n3 = red16(n3);
    d01 = red16(d01); d02 = red16(d02); d03 = red16(d03);
    d12 = red16(d12); d13 = red16(d13); d23 = red16(d23);

    const float i0 = 1.0f / fmaxf(sqrtf(n0), 1e-8f);
    const float i1 = 1.0f / fmaxf(sqrtf(n1), 1e-8f);
    const float i2 = 1.0f / fmaxf(sqrtf(n2), 1e-8f);
    const float i3 = 1.0f / fmaxf(sqrtf(n3), 1e-8f);

    // fold 1/T = 2
    const float s01 = 2.0f * d01 * i0 * i1;
    const float s02 = 2.0f * d02 * i0 * i2;
    const float s03 = 2.0f * d03 * i0 * i3;
    const float s12 = 2.0f * d12 * i1 * i2;
    const float s13 = 2.0f * d13 * i1 * i3;
    const float s23 = 2.0f * d23 * i2 * i3;

    float gl = 0.0f;
    gl += rowloss(s02, s01, s03, L.s[0], L.s[1], L.s[2]);
    gl += rowloss(s13, s01, s12, L.s[3], L.s[4], L.s[5]);
    gl += rowloss(s02, s12, s23, L.s[6], L.s[7], L.s[8]);
    gl += rowloss(s13, s03, s23, L.s[9], L.s[10], L.s[11]);
    return valid ? gl : 0.0f;
}

__global__ __launch_bounds__(256, 3) void ntxent_stage1(
    const float* __restrict__ zis, const float* __restrict__ zjs,
    const float* __restrict__ sl, float* __restrict__ partial, int nc) {
    const int lane = threadIdx.x & 63;
    const int wid  = threadIdx.x >> 6;
    const int t    = lane & 15;
    const int q    = lane >> 4;
    const int o    = t * 4;

    const int gwave = blockIdx.x * 4 + wid;
    const int nwave = gridDim.x * 4;
    const int nquad = (nc + 3) >> 2;

    SL L;
#pragma unroll
    for (int i = 0; i < 12; ++i) L.s[i] = sl[i];

    float wsum = 0.0f;
    float4 vA[16], vB[16];

    int quad = gwave;
    if (quad < nquad) {
        {
            const int g = quad * 4 + q;
            load_quad(vA, zis, zjs, (g < nc) ? g : 0, o);
        }
        while (true) {
            const int qB = quad + nwave;
            if (qB < nquad) {
                const int g = qB * 4 + q;
                load_quad(vB, zis, zjs, (g < nc) ? g : 0, o);
            }
            wsum += compute_quad(vA, (quad * 4 + q) < nc, L);
            if (qB >= nquad) break;

            const int qA = qB + nwave;
            if (qA < nquad) {
                const int g = qA * 4 + q;
                load_quad(vA, zis, zjs, (g < nc) ? g : 0, o);
            }
            wsum += compute_quad(vB, (qB * 4 + q) < nc, L);
            if (qA >= nquad) break;
            quad = qA;
        }
    }
    wsum *= 0.0625f;   // 16 redundant lanes per subgroup

#pragma unroll
    for (int off = 1; off < 64; off <<= 1) wsum += __shfl_xor(wsum, off);

    __shared__ float smem[4];
    if (lane == 0) smem[wid] = wsum;
    __syncthreads();
    if (threadIdx.x == 0)
        partial[blockIdx.x] = smem[0] + smem[1] + smem[2] + smem[3];
}

__global__ __launch_bounds__(256) void ntxent_stage2(
    const float* __restrict__ partial, int nparts, double inv_div,
    float* __restrict__ out) {
    double acc = 0.0;
    for (int i = threadIdx.x; i < nparts; i += 256) acc += (double)partial[i];
#pragma unroll
    for (int off = 1; off < 64; off <<= 1) acc += __shfl_xor(acc, off);
    __shared__ double sm[4];
    const int wid = threadIdx.x >> 6;
    if ((threadIdx.x & 63) == 0) sm[wid] = acc;
    __syncthreads();
    if (threadIdx.x == 0) out[0] = (float)((sm[0] + sm[1] + sm[2] + sm[3]) * inv_div);
}

extern "C" void kernel_launch(void* const* d_in, const int* in_sizes, int n_in,
                              void* d_out, int out_size, void* d_ws, size_t ws_size,
                              hipStream_t stream) {
    const float* zis = (const float*)d_in[0];
    const float* zjs = (const float*)d_in[1];
    const float* sl  = (const float*)d_in[2];
    float* out = (float*)d_out;
    float* partial = (float*)d_ws;

    const int n  = in_sizes[0] / D;   // 65536 rows
    const int nc = n / 2;             // 32768 groups

    // 512 blocks = 2/CU, 8 waves/CU; 2048 waves x 4 quads each, prefetched.
    const int blocks = 512;
    ntxent_stage1<<<blocks, 256, 0, stream>>>(zis, zjs, sl, partial, nc);

    const double inv_div = 1.0 / (2.0 * (double)n);
    ntxent_stage2<<<1, 256, 0, stream>>>(partial, blocks, inv_div, out);
}

// Round 7
// 147.085 us; speedup vs baseline: 1.2393x; 1.2393x over previous
//
#include <hip/hip_runtime.h>
#include <math.h>

// DynamicNTXentLoss on MI355X — r5: persistent waves + spill-proof
// software pipeline (named-register double buffer, unconditional loads).
//
// r4 post-mortem: float4 vA[16]/vB[16] + conditional load_quad() calls →
// SROA failure → scratch spill (WRITE_SIZE 116 MB, VGPR=84, 81 µs).
// r5: two 8-register sets A0..A7/B0..B7 as NAMED float4 scalars via
// macros; every load is unconditional with a clamped group index and the
// accumulate is masked; straight-line loop body so the compiler emits
// counted vmcnt and keeps 16 loads in flight per wave.
//
// Layout: wave = 4 subgroups x 16 lanes; subgroup q handles group quad*4+q.
// Lane t owns bytes [t*16, t*16+16) of each 256 B half-row chunk.
// Half h of a quad = floats [h*128, h*128+128) of each of the 4 rows
// (row0=zjs[2g], row1=zjs[2g+1], row2=zis[2g], row3=zis[2g+1]).

constexpr int D = 256;

__device__ __forceinline__ float dot4(float4 a, float4 b) {
    return fmaf(a.x, b.x, fmaf(a.y, b.y, fmaf(a.z, b.z, a.w * b.w)));
}

template <int CTRL>
__device__ __forceinline__ float dpp_add(float x) {
    int y = __builtin_amdgcn_update_dpp(0, __float_as_int(x), CTRL, 0xF, 0xF, true);
    return x + __int_as_float(y);
}

// sum across the 16-lane subgroup; all 16 lanes get the total
__device__ __forceinline__ float red16(float x) {
    x = dpp_add<0xB1>(x);   // quad_perm xor1
    x = dpp_add<0x4E>(x);   // quad_perm xor2
    x = dpp_add<0x124>(x);  // row_ror:4
    x = dpp_add<0x128>(x);  // row_ror:8
    return x;
}

__device__ __forceinline__ float rowloss(float a, float b, float c,
                                         float s0, float s1, float s2) {
    float m = fmaxf(fmaxf(a, b), c);
    float lse = m + __logf(__expf(a - m) + __expf(b - m) + __expf(c - m));
    return s0 * (lse - a) + s1 * (lse - b) + s2 * (lse - c);
}

// load half H (0/1) of quad-group G's 4 rows into named regs P0..P7
#define LOAD8(P, G, H)                                             \
    {                                                              \
        const float* _rj = zjs + (size_t)(2 * (G)) * D + (H)*128 + o; \
        const float* _ri = zis + (size_t)(2 * (G)) * D + (H)*128 + o; \
        P##0 = *(const float4*)(_rj);                              \
        P##1 = *(const float4*)(_rj + 64);                         \
        P##2 = *(const float4*)(_rj + D);                          \
        P##3 = *(const float4*)(_rj + D + 64);                     \
        P##4 = *(const float4*)(_ri);                              \
        P##5 = *(const float4*)(_ri + 64);                         \
        P##6 = *(const float4*)(_ri + D);                          \
        P##7 = *(const float4*)(_ri + D + 64);                     \
    }

// accumulate half-quad P0..P7 into the 10 running dot products
#define ACC8(P)                                                    \
    {                                                              \
        n0  += dot4(P##0, P##0) + dot4(P##1, P##1);                \
        n1  += dot4(P##2, P##2) + dot4(P##3, P##3);                \
        n2  += dot4(P##4, P##4) + dot4(P##5, P##5);                \
        n3  += dot4(P##6, P##6) + dot4(P##7, P##7);                \
        d01 += dot4(P##0, P##2) + dot4(P##1, P##3);                \
        d02 += dot4(P##0, P##4) + dot4(P##1, P##5);                \
        d03 += dot4(P##0, P##6) + dot4(P##1, P##7);                \
        d12 += dot4(P##2, P##4) + dot4(P##3, P##5);                \
        d13 += dot4(P##2, P##6) + dot4(P##3, P##7);                \
        d23 += dot4(P##4, P##6) + dot4(P##5, P##7);                \
    }

__global__ __launch_bounds__(256, 4) void ntxent_stage1(
    const float* __restrict__ zis, const float* __restrict__ zjs,
    const float* __restrict__ sl, float* __restrict__ partial, int nc) {
    const int lane = threadIdx.x & 63;
    const int wid  = threadIdx.x >> 6;
    const int t    = lane & 15;
    const int q    = lane >> 4;
    const int o    = t * 4;

    const int gwave = blockIdx.x * 4 + wid;
    const int nwave = gridDim.x * 4;
    const int nquad = (nc + 3) >> 2;

    const float sl00 = sl[0],  sl01 = sl[1],  sl02 = sl[2];
    const float sl10 = sl[3],  sl11 = sl[4],  sl12 = sl[5];
    const float sl20 = sl[6],  sl21 = sl[7],  sl22 = sl[8];
    const float sl30 = sl[9],  sl31 = sl[10], sl32 = sl[11];

    float wsum = 0.0f;

    if (gwave < nquad) {
        float4 A0, A1, A2, A3, A4, A5, A6, A7;
        float4 B0, B1, B2, B3, B4, B5, B6, B7;
        float n0 = 0, n1 = 0, n2 = 0, n3 = 0;
        float d01 = 0, d02 = 0, d03 = 0, d12 = 0, d13 = 0, d23 = 0;

        int k = gwave;
        int g = k * 4 + q;
        bool valid = g < nc;
        int gc = valid ? g : (nc - 1);

        LOAD8(A, gc, 0);             // prologue: half0 of first quad
        while (true) {
            LOAD8(B, gc, 1);         // half1 of current quad
            ACC8(A);                 // consume half0 (vmcnt(8): B stays in flight)

            const int kn = k + nwave;
            const bool more = kn < nquad;
            const int gn = kn * 4 + q;
            const bool validn = more && (gn < nc);
            const int gcn = more ? (validn ? gn : (nc - 1)) : gc;

            LOAD8(A, gcn, 0);        // prefetch half0 of next quad
            ACC8(B);                 // consume half1

            // ---- epilogue for quad k ----
            {
                float r0 = red16(n0), r1 = red16(n1), r2 = red16(n2), r3 = red16(n3);
                float e01 = red16(d01), e02 = red16(d02), e03 = red16(d03);
                float e12 = red16(d12), e13 = red16(d13), e23 = red16(d23);

                const float i0 = 1.0f / fmaxf(sqrtf(r0), 1e-8f);
                const float i1 = 1.0f / fmaxf(sqrtf(r1), 1e-8f);
                const float i2 = 1.0f / fmaxf(sqrtf(r2), 1e-8f);
                const float i3 = 1.0f / fmaxf(sqrtf(r3), 1e-8f);

                // fold 1/T = 2
                const float s01 = 2.0f * e01 * i0 * i1;
                const float s02 = 2.0f * e02 * i0 * i2;
                const float s03 = 2.0f * e03 * i0 * i3;
                const float s12 = 2.0f * e12 * i1 * i2;
                const float s13 = 2.0f * e13 * i1 * i3;
                const float s23 = 2.0f * e23 * i2 * i3;

                float gl = 0.0f;
                gl += rowloss(s02, s01, s03, sl00, sl01, sl02);
                gl += rowloss(s13, s01, s12, sl10, sl11, sl12);
                gl += rowloss(s02, s12, s23, sl20, sl21, sl22);
                gl += rowloss(s13, s03, s23, sl30, sl31, sl32);
                wsum += valid ? gl : 0.0f;

                n0 = n1 = n2 = n3 = 0.0f;
                d01 = d02 = d03 = d12 = d13 = d23 = 0.0f;
            }

            if (!more) break;
            k = kn; gc = gcn; valid = validn;
        }
    }
    wsum *= 0.0625f;   // 16 redundant lanes per subgroup

#pragma unroll
    for (int off = 1; off < 64; off <<= 1) wsum += __shfl_xor(wsum, off);

    __shared__ float smem[4];
    if (lane == 0) smem[wid] = wsum;
    __syncthreads();
    if (threadIdx.x == 0)
        partial[blockIdx.x] = smem[0] + smem[1] + smem[2] + smem[3];
}

__global__ __launch_bounds__(256) void ntxent_stage2(
    const float* __restrict__ partial, int nparts, double inv_div,
    float* __restrict__ out) {
    double acc = 0.0;
    for (int i = threadIdx.x; i < nparts; i += 256) acc += (double)partial[i];
#pragma unroll
    for (int off = 1; off < 64; off <<= 1) acc += __shfl_xor(acc, off);
    __shared__ double sm[4];
    const int wid = threadIdx.x >> 6;
    if ((threadIdx.x & 63) == 0) sm[wid] = acc;
    __syncthreads();
    if (threadIdx.x == 0) out[0] = (float)((sm[0] + sm[1] + sm[2] + sm[3]) * inv_div);
}

extern "C" void kernel_launch(void* const* d_in, const int* in_sizes, int n_in,
                              void* d_out, int out_size, void* d_ws, size_t ws_size,
                              hipStream_t stream) {
    const float* zis = (const float*)d_in[0];
    const float* zjs = (const float*)d_in[1];
    const float* sl  = (const float*)d_in[2];
    float* out = (float*)d_out;
    float* partial = (float*)d_ws;

    const int n  = in_sizes[0] / D;   // 65536 rows
    const int nc = n / 2;             // 32768 groups

    // 512 blocks = 2/CU, 8 waves/CU; 2048 waves x 4 quads each, pipelined.
    const int blocks = 512;
    ntxent_stage1<<<blocks, 256, 0, stream>>>(zis, zjs, sl, partial, nc);

    const double inv_div = 1.0 / (2.0 * (double)n);
    ntxent_stage2<<<1, 256, 0, stream>>>(partial, blocks, inv_div, out);
}